// Round 4
// baseline (213.683 us; speedup 1.0000x reference)
//
#include <hip/hip_runtime.h>
#include <hip/hip_bf16.h>

typedef _Float16 f16;
typedef f16 f16x2 __attribute__((ext_vector_type(2)));
typedef f16 f16x4 __attribute__((ext_vector_type(4)));
typedef f16 f16x8 __attribute__((ext_vector_type(8)));
typedef float f32x4 __attribute__((ext_vector_type(4)));

#define NB   2
#define LL   2048
#define LQ   2048         // q tokens per scrambled batch
#define LKV  512          // unique kv tokens per scrambled batch
#define DD   128
#define BM   128          // q tokens per block (4 waves x 32)
#define BN   64           // kv tokens per iteration
#define KS_STR 132        // halves per Ks row (128+4)
#define VT_STR 68         // halves per Vt row (64+4)
#define PT_STR 68         // halves per Pt row (64+4)

// SEMANTICS (decoded from the reference's row-major (B,L,H,D)->(B*H,L,D) reshape):
//   batch g = 32*b + l_hi (l_hi = l/64), token t = (l%64)*32 + h, feature e = d.
//   K'/V' repeat each kv segment 4x (repeat_interleave); softmax over 4x-repeated
//   scores == softmax over the 512 unique tokens (the factor 4 cancels).
//   => 64 independent standard attentions, Lq=2048, Lkv=512, D=128:
//      Q''[g] = Q[b, 64*l_hi:+64, :]   viewed 2048x128 (contiguous)
//      K''[g] = K[b, 64*l_hi:+64, :]   viewed  512x128 (contiguous), same V
//      out[g][t][d] -> og[(b*2048 + t)*4096 + l_hi*128 + d]
// MFMA facts: end-to-end-verified 16x16x32 tuple (m89/m90-97/m120):
//   A: lane(ln=lane&15,qd=lane>>4) slot j -> A[m=ln][k=8*qd+j]
//   B: slot j -> B[k=8*qd+j][n=ln]
//   C/D: elem r -> D[row=4*qd+r][col=ln],  D = A*B + C
// Flow: S^T = K*Q^T (softmax axis in registers), P^T via LDS, O^T = V^T*P^T.
// Output dtype f32 (reference fp16 -> harness 'else float*' branch).
__global__ __launch_bounds__(256, 2)
void fa_fwd(const float* __restrict__ qg,
            const float* __restrict__ kg,
            const float* __restrict__ vg,
            float* __restrict__ og)
{
    __shared__ __align__(16) f16 smem[BN*KS_STR + DD*VT_STR + BM*PT_STR]; // 51712 B
    f16* Ks = smem;                           // [kv 64][d 128] (+4 pad)
    f16* Vt = smem + BN*KS_STR;               // [d 128][kv 64] (+4 pad)
    f16* Pt = smem + BN*KS_STR + DD*VT_STR;   // [q 128][kv 64] (+4 pad)

    const int tid  = threadIdx.x;
    const int wave = tid >> 6;
    const int lane = tid & 63;
    const int ln   = lane & 15;
    const int qd   = lane >> 4;

    const int qt   = blockIdx.x;        // 0..15
    const int g    = blockIdx.y;        // 0..63
    const int bb   = g >> 5;
    const int lhi  = g & 31;

    const float* qmat = qg + (size_t)(bb*LL + 64*lhi)*4096;  // [2048][128]
    const float* kmat = kg + (size_t)(bb*LL + 64*lhi)*1024;  // [512][128]
    const float* vmat = vg + (size_t)(bb*LL + 64*lhi)*1024;  // [512][128]

    const int qbase = qt*BM + wave*32;

    // Q fragments: B-operand of S^T=K*Q^T. frag(nt,kc) slot j = Q''[qbase+16nt+ln][32kc+8qd+j]
    f16x8 qf[2][4];
#pragma unroll
    for (int nt = 0; nt < 2; ++nt) {
        const float* qrow = qmat + (size_t)(qbase + 16*nt + ln)*DD;
#pragma unroll
        for (int kc = 0; kc < 4; ++kc) {
            const float4* qp = (const float4*)(qrow + kc*32 + 8*qd);
            float4 f0 = qp[0], f1 = qp[1];
            f16x8 t = { (f16)f0.x,(f16)f0.y,(f16)f0.z,(f16)f0.w,
                        (f16)f1.x,(f16)f1.y,(f16)f1.z,(f16)f1.w };
            qf[nt][kc] = t;
        }
    }

    f32x4 o[2][8];   // o[nt][dmt][r] = O^T[16*dmt+4*qd+r][q(nt)]
#pragma unroll
    for (int nt = 0; nt < 2; ++nt)
#pragma unroll
        for (int dmt = 0; dmt < 8; ++dmt)
#pragma unroll
            for (int r = 0; r < 4; ++r) o[nt][dmt][r] = 0.0f;

    float mrun[2] = {-1e30f, -1e30f}, lrun[2] = {0.0f, 0.0f};
    // reference multiplies by jnp.float16(1/sqrt(128)) -> use the fp16-rounded scale
    const float SC2 = 0.08837890625f * 1.44269504088896340f;

    for (int kt = 0; kt < LKV/BN; ++kt) {
        const float* kb = kmat + kt*BN*DD;   // contiguous [64][128] tile
        const float* vb = vmat + kt*BN*DD;

        // ---- stage K rows -> Ks[kv][d], perfectly coalesced (tile is contiguous) ----
#pragma unroll
        for (int i = 0; i < 8; ++i) {
            int f = tid + i*256;
            int row = f >> 5, c4 = f & 31;
            float4 x = *(const float4*)(kb + f*4);
            f16x4 h4 = { (f16)x.x,(f16)x.y,(f16)x.z,(f16)x.w };
            *(f16x4*)(Ks + row*KS_STR + c4*4) = h4;
        }
        // ---- stage V transposed -> Vt[d][kv] ----
#pragma unroll
        for (int i = 0; i < 8; ++i) {
            int f = tid + i*256;
            int kvr = f & 63, c4 = f >> 6;
            float4 x = *(const float4*)(vb + (size_t)kvr*DD + c4*4);
            Vt[(c4*4+0)*VT_STR + kvr] = (f16)x.x;
            Vt[(c4*4+1)*VT_STR + kvr] = (f16)x.y;
            Vt[(c4*4+2)*VT_STR + kvr] = (f16)x.z;
            Vt[(c4*4+3)*VT_STR + kvr] = (f16)x.w;
        }
        __syncthreads();

        // ---- S^T = K*Q^T : 4 kv-tiles x 2 q-tiles, K=128 in 4 chunks of 32 ----
        f32x4 st[2][4];  // st[nt][mt][r] = S^T[16*mt+4*qd+r][q(nt)]
#pragma unroll
        for (int nt = 0; nt < 2; ++nt)
#pragma unroll
            for (int mt = 0; mt < 4; ++mt)
#pragma unroll
                for (int r = 0; r < 4; ++r) st[nt][mt][r] = 0.0f;
#pragma unroll
        for (int mt = 0; mt < 4; ++mt) {
            const f16* kr = Ks + (16*mt + ln)*KS_STR + 8*qd;
#pragma unroll
            for (int kc = 0; kc < 4; ++kc) {
                f16x4 a0 = *(const f16x4*)(kr + kc*32);
                f16x4 a1 = *(const f16x4*)(kr + kc*32 + 4);
                f16x8 af = __builtin_shufflevector(a0, a1, 0,1,2,3,4,5,6,7);
#pragma unroll
                for (int nt = 0; nt < 2; ++nt)
                    st[nt][mt] = __builtin_amdgcn_mfma_f32_16x16x32_f16(af, qf[nt][kc], st[nt][mt], 0,0,0);
            }
        }

        // ---- online softmax over kv (in-lane + shfl_xor 16,32) ----
        float alph[2];
#pragma unroll
        for (int nt = 0; nt < 2; ++nt) {
            float mx = -1e30f;
#pragma unroll
            for (int mt = 0; mt < 4; ++mt)
#pragma unroll
                for (int r = 0; r < 4; ++r) {
                    float v = st[nt][mt][r]*SC2; st[nt][mt][r] = v; mx = fmaxf(mx, v);
                }
            mx = fmaxf(mx, __shfl_xor(mx, 16, 64));
            mx = fmaxf(mx, __shfl_xor(mx, 32, 64));
            float mnew = fmaxf(mrun[nt], mx);
            alph[nt] = exp2f(mrun[nt] - mnew);
            float rs = 0.0f;
#pragma unroll
            for (int mt = 0; mt < 4; ++mt)
#pragma unroll
                for (int r = 0; r < 4; ++r) {
                    float p = exp2f(st[nt][mt][r] - mnew);
                    st[nt][mt][r] = p; rs += p;
                }
            rs += __shfl_xor(rs, 16, 64);
            rs += __shfl_xor(rs, 32, 64);
            lrun[nt] = lrun[nt]*alph[nt] + rs;
            mrun[nt] = mnew;
        }

        // ---- P -> LDS (C/D-layout write): Pt[q][kv] ----
#pragma unroll
        for (int nt = 0; nt < 2; ++nt) {
            f16* prow = Pt + (wave*32 + 16*nt + ln)*PT_STR + 4*qd;
#pragma unroll
            for (int mt = 0; mt < 4; ++mt)
#pragma unroll
                for (int p2 = 0; p2 < 2; ++p2) {
                    f16x2 pp = { (f16)st[nt][mt][2*p2], (f16)st[nt][mt][2*p2+1] };
                    *(f16x2*)(prow + 16*mt + 2*p2) = pp;
                }
        }

        // ---- rescale O^T by alpha ----
#pragma unroll
        for (int nt = 0; nt < 2; ++nt)
#pragma unroll
            for (int dmt = 0; dmt < 8; ++dmt)
#pragma unroll
                for (int r = 0; r < 4; ++r) o[nt][dmt][r] *= alph[nt];

        // ---- O^T += V^T * P^T : A = Vt rows, B = Pt rows (B-layout read) ----
#pragma unroll
        for (int kc2 = 0; kc2 < 2; ++kc2) {
            f16x8 pf[2];
#pragma unroll
            for (int nt = 0; nt < 2; ++nt) {
                const f16* pr = Pt + (wave*32 + 16*nt + ln)*PT_STR + kc2*32 + 8*qd;
                f16x4 b0 = *(const f16x4*)(pr);
                f16x4 b1 = *(const f16x4*)(pr + 4);
                pf[nt] = __builtin_shufflevector(b0, b1, 0,1,2,3,4,5,6,7);
            }
#pragma unroll
            for (int dmt = 0; dmt < 8; ++dmt) {
                const f16* vr = Vt + (16*dmt + ln)*VT_STR + kc2*32 + 8*qd;
                f16x4 a0 = *(const f16x4*)(vr);
                f16x4 a1 = *(const f16x4*)(vr + 4);
                f16x8 vf = __builtin_shufflevector(a0, a1, 0,1,2,3,4,5,6,7);
#pragma unroll
                for (int nt = 0; nt < 2; ++nt)
                    o[nt][dmt] = __builtin_amdgcn_mfma_f32_16x16x32_f16(vf, pf[nt], o[nt][dmt], 0,0,0);
            }
        }
        __syncthreads();   // protect Ks/Vt before next staging
    }

    // ---- epilogue: O^T/l -> f32; out[g][t][d] -> og[(bb*2048+t)*4096 + lhi*128 + d] ----
#pragma unroll
    for (int nt = 0; nt < 2; ++nt) {
        float inv = 1.0f / lrun[nt];
        int qtok = qbase + 16*nt + ln;
        float* orow = og + (size_t)(bb*LL + qtok)*4096 + lhi*DD + 4*qd;
#pragma unroll
        for (int dmt = 0; dmt < 8; ++dmt) {
            float4 x = { o[nt][dmt][0]*inv, o[nt][dmt][1]*inv,
                         o[nt][dmt][2]*inv, o[nt][dmt][3]*inv };
            *(float4*)(orow + 16*dmt) = x;
        }
    }
}

extern "C" void kernel_launch(void* const* d_in, const int* in_sizes, int n_in,
                              void* d_out, int out_size, void* d_ws, size_t ws_size,
                              hipStream_t stream) {
    (void)in_sizes; (void)n_in; (void)out_size; (void)d_ws; (void)ws_size;
    const float* q = (const float*)d_in[0];
    const float* k = (const float*)d_in[1];
    const float* v = (const float*)d_in[2];
    float* o = (float*)d_out;
    dim3 grid(LQ/BM, 64, 1), block(256);
    hipLaunchKernelGGL(fa_fwd, grid, block, 0, stream, q, k, v, o);
}